// Round 1
// baseline (40257.120 us; speedup 1.0000x reference)
//
#include <hip/hip_runtime.h>
#include <math.h>

#define BB 128
#define TT 256
#define HH 512
#define VV 32
#define MLEN 128

__device__ __forceinline__ float sigmoidf_(float v) { return 1.0f / (1.0f + expf(-v)); }

// ---------------------------------------------------------------------------
// zero init: enc h0 slot1, enc h1 slot0
__global__ __launch_bounds__(256) void k_zero2(float* __restrict__ a, float* __restrict__ b)
{
    int i = blockIdx.x * 256 + threadIdx.x;
    if (i < HH * BB) { a[i] = 0.0f; b[i] = 0.0f; }
}

// ---------------------------------------------------------------------------
// Encoder step (pipelined): z==0 -> layer0 step t (t<256); z==1 -> layer1 step t-1 (t>=1)
// All hidden buffers d-major: h[d*128 + b]
__global__ __launch_bounds__(256) void k_enc_step(
    int t,
    const float* __restrict__ x,
    const float* __restrict__ Wih0, const float* __restrict__ Whh0,
    const float* __restrict__ bih0, const float* __restrict__ bhh0,
    const float* __restrict__ Wih1, const float* __restrict__ Whh1,
    const float* __restrict__ bih1, const float* __restrict__ bhh1,
    const float* __restrict__ h0src, float* __restrict__ h0dst,
    const float* __restrict__ h1src, float* __restrict__ h1dst,
    float* __restrict__ encO)
{
    const int lane = threadIdx.x & 63;
    const int b = blockIdx.y * 64 + lane;
    int j = __builtin_amdgcn_readfirstlane((int)(blockIdx.x * 4 + (threadIdx.x >> 6)));

    if (blockIdx.z == 0) {
        if (t >= TT) return;
        const float* wr = Whh0 + (size_t)j * HH;
        const float* wz = Whh0 + (size_t)(j + HH) * HH;
        const float* wn = Whh0 + (size_t)(j + 2 * HH) * HH;
        float ar = bhh0[j], az = bhh0[j + HH], an = bhh0[j + 2 * HH];
#pragma unroll 8
        for (int d = 0; d < HH; d++) {
            float a = h0src[d * BB + b];
            ar = fmaf(wr[d], a, ar);
            az = fmaf(wz[d], a, az);
            an = fmaf(wn[d], a, an);
        }
        float x0 = x[((size_t)b * TT + t) * 2 + 0];
        float x1 = x[((size_t)b * TT + t) * 2 + 1];
        float ir = fmaf(Wih0[j * 2 + 1], x1, fmaf(Wih0[j * 2 + 0], x0, bih0[j]));
        float iz = fmaf(Wih0[(j + HH) * 2 + 1], x1, fmaf(Wih0[(j + HH) * 2 + 0], x0, bih0[j + HH]));
        float in_ = fmaf(Wih0[(j + 2 * HH) * 2 + 1], x1, fmaf(Wih0[(j + 2 * HH) * 2 + 0], x0, bih0[j + 2 * HH]));
        float hp = h0src[j * BB + b];
        float r = sigmoidf_(ir + ar);
        float z = sigmoidf_(iz + az);
        float n = tanhf(in_ + r * an);
        h0dst[j * BB + b] = (1.0f - z) * n + z * hp;
    } else {
        if (t < 1) return;
        const int s = t - 1;
        const float* y = h0src;  // y0_{t-1} lives in the slot layer0 reads this launch
        const float* wir = Wih1 + (size_t)j * HH;
        const float* wiz = Wih1 + (size_t)(j + HH) * HH;
        const float* win = Wih1 + (size_t)(j + 2 * HH) * HH;
        const float* whr = Whh1 + (size_t)j * HH;
        const float* whz = Whh1 + (size_t)(j + HH) * HH;
        const float* whn = Whh1 + (size_t)(j + 2 * HH) * HH;
        float ir = bih1[j], iz = bih1[j + HH], in_ = bih1[j + 2 * HH];
        float ar = bhh1[j], az = bhh1[j + HH], an = bhh1[j + 2 * HH];
#pragma unroll 8
        for (int d = 0; d < HH; d++) {
            float a = y[d * BB + b];
            ir = fmaf(wir[d], a, ir);
            iz = fmaf(wiz[d], a, iz);
            in_ = fmaf(win[d], a, in_);
        }
#pragma unroll 8
        for (int d = 0; d < HH; d++) {
            float a = h1src[d * BB + b];
            ar = fmaf(whr[d], a, ar);
            az = fmaf(whz[d], a, az);
            an = fmaf(whn[d], a, an);
        }
        float hp = h1src[j * BB + b];
        float r = sigmoidf_(ir + ar);
        float z = sigmoidf_(iz + az);
        float n = tanhf(in_ + r * an);
        float hv = (1.0f - z) * n + z * hp;
        h1dst[j * BB + b] = hv;
        encO[((size_t)b * TT + s) * HH + j] = hv;
    }
}

// ---------------------------------------------------------------------------
// decoder init: dec h states <- enc finals, embT <- emb row 0 (tok0 = 0)
__global__ __launch_bounds__(256) void k_dec_init(
    const float* __restrict__ eh0f, const float* __restrict__ eh1f,
    float* __restrict__ dh0, float* __restrict__ dh1,
    const float* __restrict__ emb, float* __restrict__ embT)
{
    int idx = blockIdx.x * 256 + threadIdx.x;
    if (idx < HH * BB) {
        dh0[idx] = eh0f[idx];
        dh1[idx] = eh1f[idx];
        embT[idx] = emb[idx >> 7];  // d = idx>>7 ; emb[0*H + d]
    }
}

// ---------------------------------------------------------------------------
// query = h1 @ qW^T + qb   (h1 d-major; qbm b-major [b*H + j])
__global__ __launch_bounds__(256) void k_query(
    const float* __restrict__ h1, const float* __restrict__ qW,
    const float* __restrict__ qb, float* __restrict__ qbm)
{
    const int lane = threadIdx.x & 63;
    const int b = blockIdx.y * 64 + lane;
    int j = __builtin_amdgcn_readfirstlane((int)(blockIdx.x * 4 + (threadIdx.x >> 6)));
    const float* w = qW + (size_t)j * HH;
    float acc = qb[j];
#pragma unroll 8
    for (int d = 0; d < HH; d++) acc = fmaf(w[d], h1[d * BB + b], acc);
    qbm[(size_t)b * HH + j] = acc;
}

// ---------------------------------------------------------------------------
// attention: scores -> softmax -> context; one block per batch row
__global__ __launch_bounds__(256) void k_attn(
    int s, const float* __restrict__ qbm, const float* __restrict__ encO,
    float* __restrict__ ctx, float* __restrict__ attnO)
{
    const int b = blockIdx.x;
    const int tid = threadIdx.x;
    __shared__ float qs[HH];
    __shared__ float wsm[TT];
    __shared__ float red[256];
    __shared__ float part[8][HH];

    qs[tid] = qbm[(size_t)b * HH + tid];
    qs[tid + 256] = qbm[(size_t)b * HH + tid + 256];
    __syncthreads();

    // scores: thread tid handles t = tid
    const float4* E4 = (const float4*)(encO + ((size_t)b * TT + tid) * HH);
    float acc = 0.0f;
#pragma unroll 8
    for (int i = 0; i < HH / 4; i++) {
        float4 e = E4[i];
        acc += e.x * qs[4 * i] + e.y * qs[4 * i + 1] + e.z * qs[4 * i + 2] + e.w * qs[4 * i + 3];
    }
    red[tid] = acc;
    __syncthreads();
    for (int off = 128; off > 0; off >>= 1) {
        if (tid < off) red[tid] = fmaxf(red[tid], red[tid + off]);
        __syncthreads();
    }
    float m = red[0];
    __syncthreads();
    float e = expf(acc - m);
    red[tid] = e;
    __syncthreads();
    for (int off = 128; off > 0; off >>= 1) {
        if (tid < off) red[tid] += red[tid + off];
        __syncthreads();
    }
    float w = e / red[0];
    wsm[tid] = w;
    attnO[((size_t)b * MLEN + s) * TT + tid] = w;
    __syncthreads();

    // context: 8 t-groups x 32 h-lanes, 16 h per thread
    const int tg = tid >> 5, hg = tid & 31;
    float pacc[16];
#pragma unroll
    for (int k = 0; k < 16; k++) pacc[k] = 0.0f;
    for (int tt = tg * 32; tt < tg * 32 + 32; tt++) {
        float wl = wsm[tt];
        const float* E2 = encO + ((size_t)b * TT + tt) * HH;
#pragma unroll
        for (int k = 0; k < 16; k++) pacc[k] = fmaf(wl, E2[hg + 32 * k], pacc[k]);
    }
#pragma unroll
    for (int k = 0; k < 16; k++) part[tg][hg + 32 * k] = pacc[k];
    __syncthreads();
    for (int h = tid; h < HH; h += 256) {
        float c = 0.0f;
#pragma unroll
        for (int g = 0; g < 8; g++) c += part[g][h];
        ctx[h * BB + b] = c;  // d-major
    }
}

// ---------------------------------------------------------------------------
// decoder GRU layer0: input = [embedded ; context] (both d-major), D=1024
__global__ __launch_bounds__(256) void k_gru0(
    const float* __restrict__ embT, const float* __restrict__ ctx,
    const float* __restrict__ Wih, const float* __restrict__ Whh,
    const float* __restrict__ bih, const float* __restrict__ bhh,
    const float* __restrict__ hsrc, float* __restrict__ hdst)
{
    const int lane = threadIdx.x & 63;
    const int b = blockIdx.y * 64 + lane;
    int j = __builtin_amdgcn_readfirstlane((int)(blockIdx.x * 4 + (threadIdx.x >> 6)));
    const float* wir = Wih + (size_t)j * 1024;
    const float* wiz = Wih + (size_t)(j + HH) * 1024;
    const float* win = Wih + (size_t)(j + 2 * HH) * 1024;
    float ir = bih[j], iz = bih[j + HH], in_ = bih[j + 2 * HH];
#pragma unroll 8
    for (int d = 0; d < HH; d++) {
        float a = embT[d * BB + b];
        ir = fmaf(wir[d], a, ir);
        iz = fmaf(wiz[d], a, iz);
        in_ = fmaf(win[d], a, in_);
    }
#pragma unroll 8
    for (int d = 0; d < HH; d++) {
        float a = ctx[d * BB + b];
        ir = fmaf(wir[HH + d], a, ir);
        iz = fmaf(wiz[HH + d], a, iz);
        in_ = fmaf(win[HH + d], a, in_);
    }
    const float* whr = Whh + (size_t)j * HH;
    const float* whz = Whh + (size_t)(j + HH) * HH;
    const float* whn = Whh + (size_t)(j + 2 * HH) * HH;
    float ar = bhh[j], az = bhh[j + HH], an = bhh[j + 2 * HH];
#pragma unroll 8
    for (int d = 0; d < HH; d++) {
        float a = hsrc[d * BB + b];
        ar = fmaf(whr[d], a, ar);
        az = fmaf(whz[d], a, az);
        an = fmaf(whn[d], a, an);
    }
    float hp = hsrc[j * BB + b];
    float r = sigmoidf_(ir + ar);
    float z = sigmoidf_(iz + az);
    float n = tanhf(in_ + r * an);
    hdst[j * BB + b] = (1.0f - z) * n + z * hp;
}

// ---------------------------------------------------------------------------
// decoder GRU layer1: input = g0 (d-major), D=512
__global__ __launch_bounds__(256) void k_gru1(
    const float* __restrict__ g0,
    const float* __restrict__ Wih, const float* __restrict__ Whh,
    const float* __restrict__ bih, const float* __restrict__ bhh,
    const float* __restrict__ hsrc, float* __restrict__ hdst)
{
    const int lane = threadIdx.x & 63;
    const int b = blockIdx.y * 64 + lane;
    int j = __builtin_amdgcn_readfirstlane((int)(blockIdx.x * 4 + (threadIdx.x >> 6)));
    const float* wir = Wih + (size_t)j * HH;
    const float* wiz = Wih + (size_t)(j + HH) * HH;
    const float* win = Wih + (size_t)(j + 2 * HH) * HH;
    const float* whr = Whh + (size_t)j * HH;
    const float* whz = Whh + (size_t)(j + HH) * HH;
    const float* whn = Whh + (size_t)(j + 2 * HH) * HH;
    float ir = bih[j], iz = bih[j + HH], in_ = bih[j + 2 * HH];
    float ar = bhh[j], az = bhh[j + HH], an = bhh[j + 2 * HH];
#pragma unroll 8
    for (int d = 0; d < HH; d++) {
        float a = g0[d * BB + b];
        ir = fmaf(wir[d], a, ir);
        iz = fmaf(wiz[d], a, iz);
        in_ = fmaf(win[d], a, in_);
    }
#pragma unroll 8
    for (int d = 0; d < HH; d++) {
        float a = hsrc[d * BB + b];
        ar = fmaf(whr[d], a, ar);
        az = fmaf(whz[d], a, az);
        an = fmaf(whn[d], a, an);
    }
    float hp = hsrc[j * BB + b];
    float r = sigmoidf_(ir + ar);
    float z = sigmoidf_(iz + az);
    float n = tanhf(in_ + r * an);
    hdst[j * BB + b] = (1.0f - z) * n + z * hp;
}

// ---------------------------------------------------------------------------
// combined: (y<2) query for next step | (y==2) logits + argmax + embT update
__global__ __launch_bounds__(256) void k_out(
    int s, const float* __restrict__ h1,
    const float* __restrict__ outW, const float* __restrict__ outb,
    const float* __restrict__ qW, const float* __restrict__ qb,
    const float* __restrict__ emb, float* __restrict__ embT,
    float* __restrict__ qbm, float* __restrict__ vecO)
{
    if (blockIdx.y < 2) {
        const int lane = threadIdx.x & 63;
        const int b = blockIdx.y * 64 + lane;
        int j = __builtin_amdgcn_readfirstlane((int)(blockIdx.x * 4 + (threadIdx.x >> 6)));
        const float* w = qW + (size_t)j * HH;
        float acc = qb[j];
#pragma unroll 8
        for (int d = 0; d < HH; d++) acc = fmaf(w[d], h1[d * BB + b], acc);
        qbm[(size_t)b * HH + j] = acc;
    } else {
        const int b = blockIdx.x;
        const int tid = threadIdx.x;
        __shared__ float hs[HH];
        __shared__ float lred[VV][8];
        __shared__ float lg[VV];
        __shared__ int bestI;
        hs[tid] = h1[tid * BB + b];
        hs[tid + 256] = h1[(tid + 256) * BB + b];
        __syncthreads();
        const int v = tid >> 3, p = tid & 7;
        const float* w = outW + (size_t)v * HH + p * 64;
        const float* hp = hs + p * 64;
        float acc = 0.0f;
#pragma unroll
        for (int d = 0; d < 64; d++) acc = fmaf(w[d], hp[d], acc);
        lred[v][p] = acc;
        __syncthreads();
        if (tid < VV) {
            float l = outb[tid];
#pragma unroll
            for (int g = 0; g < 8; g++) l += lred[tid][g];
            lg[tid] = l;
            vecO[((size_t)b * MLEN + s) * VV + tid] = l;
        }
        __syncthreads();
        if (tid == 0) {
            float best = lg[0];
            int bi = 0;
            for (int v2 = 1; v2 < VV; v2++) {
                if (lg[v2] > best) { best = lg[v2]; bi = v2; }  // strict > keeps first max (jnp.argmax)
            }
            bestI = bi;
        }
        __syncthreads();
        const int bi = bestI;
        for (int d = tid; d < HH; d += 256) embT[d * BB + b] = emb[(size_t)bi * HH + d];
    }
}

// ---------------------------------------------------------------------------
// final hidden: out[l][b][h] = h_l[h*128 + b]
__global__ __launch_bounds__(256) void k_hid(
    const float* __restrict__ d0, const float* __restrict__ d1, float* __restrict__ outHid)
{
    int idx = blockIdx.x * 256 + threadIdx.x;  // 0 .. 131071
    int l = idx >> 16;
    int rem = idx & 65535;
    int b = rem >> 9;
    int h = rem & 511;
    const float* src = l ? d1 : d0;
    outHid[idx] = src[h * BB + b];
}

// ---------------------------------------------------------------------------
extern "C" void kernel_launch(void* const* d_in, const int* in_sizes, int n_in,
                              void* d_out, int out_size, void* d_ws, size_t ws_size,
                              hipStream_t stream)
{
    (void)in_sizes; (void)n_in; (void)out_size; (void)ws_size;
    const float* x     = (const float*)d_in[0];
    const float* emb   = (const float*)d_in[1];
    const float* eWih0 = (const float*)d_in[2];
    const float* eWhh0 = (const float*)d_in[3];
    const float* ebih0 = (const float*)d_in[4];
    const float* ebhh0 = (const float*)d_in[5];
    const float* eWih1 = (const float*)d_in[6];
    const float* eWhh1 = (const float*)d_in[7];
    const float* ebih1 = (const float*)d_in[8];
    const float* ebhh1 = (const float*)d_in[9];
    const float* dWih0 = (const float*)d_in[10];
    const float* dWhh0 = (const float*)d_in[11];
    const float* dbih0 = (const float*)d_in[12];
    const float* dbhh0 = (const float*)d_in[13];
    const float* dWih1 = (const float*)d_in[14];
    const float* dWhh1 = (const float*)d_in[15];
    const float* dbih1 = (const float*)d_in[16];
    const float* dbhh1 = (const float*)d_in[17];
    const float* qW    = (const float*)d_in[18];
    const float* qb    = (const float*)d_in[19];
    const float* outW  = (const float*)d_in[20];
    const float* outb  = (const float*)d_in[21];

    const int S = HH * BB;  // 65536 floats per hidden-state slot
    float* f    = (float*)d_ws;
    float* eh0  = f;               // 2 slots
    float* eh1  = f + 2 * S;       // 2 slots
    float* dh0  = f + 4 * S;       // 2 slots
    float* dh1  = f + 6 * S;       // 2 slots
    float* ctx  = f + 8 * S;
    float* qbm  = f + 9 * S;
    float* embT = f + 10 * S;
    float* encO = f + 11 * S;      // 128*256*512 floats (64 MB)

    float* vecO  = (float*)d_out;                    // [128][128][32]
    float* hidO  = vecO + (size_t)BB * MLEN * VV;    // [2][128][512]
    float* attnO = hidO + (size_t)2 * BB * HH;       // [128][128][256]

    // encoder: zero h0 slot1 (read at t=0) and h1 slot0 (read at t=1)
    k_zero2<<<256, 256, 0, stream>>>(eh0 + S, eh1);
    for (int t = 0; t <= TT; t++) {
        const float* h0s = eh0 + ((t + 1) & 1) * S;
        float*       h0d = eh0 + (t & 1) * S;
        const float* h1s = eh1 + ((t + 1) & 1) * S;
        float*       h1d = eh1 + (t & 1) * S;
        k_enc_step<<<dim3(128, 2, 2), 256, 0, stream>>>(
            t, x, eWih0, eWhh0, ebih0, ebhh0, eWih1, eWhh1, ebih1, ebhh1,
            h0s, h0d, h1s, h1d, encO);
    }
    // enc finals: h0 in slot1 (t=255), h1 in slot0 (t=256). Decoder step 0 reads slot1.
    k_dec_init<<<256, 256, 0, stream>>>(eh0 + S, eh1, dh0 + S, dh1 + S, emb, embT);
    k_query<<<dim3(128, 2), 256, 0, stream>>>(dh1 + S, qW, qb, qbm);

    for (int s = 0; s < MLEN; s++) {
        const float* h0s = dh0 + ((s + 1) & 1) * S;
        float*       h0d = dh0 + (s & 1) * S;
        const float* h1s = dh1 + ((s + 1) & 1) * S;
        float*       h1d = dh1 + (s & 1) * S;
        k_attn<<<128, 256, 0, stream>>>(s, qbm, encO, ctx, attnO);
        k_gru0<<<dim3(128, 2), 256, 0, stream>>>(embT, ctx, dWih0, dWhh0, dbih0, dbhh0, h0s, h0d);
        k_gru1<<<dim3(128, 2), 256, 0, stream>>>(h0d, dWih1, dWhh1, dbih1, dbhh1, h1s, h1d);
        k_out<<<dim3(128, 3), 256, 0, stream>>>(s, h1d, outW, outb, qW, qb, emb, embT, qbm, vecO);
    }
    // final decoder hidden: step 127 wrote slot (127&1)=1
    k_hid<<<512, 256, 0, stream>>>(dh0 + S, dh1 + S, hidO);
}